// Round 2
// baseline (433.854 us; speedup 1.0000x reference)
//
#include <hip/hip_runtime.h>
#include <hip/hip_bf16.h>

#define BATCH 8
#define CH    256
#define NTOK  4096

typedef __bf16 bf16_t;
typedef __bf16 bf16x8 __attribute__((ext_vector_type(8)));
typedef __bf16 bf16x4 __attribute__((ext_vector_type(4)));
typedef float  fx4    __attribute__((ext_vector_type(4)));

// async global->LDS, 16B per lane, dest = wave-uniform base + lane*16
#define GLOAD_LDS16(gptr, lptr) \
    __builtin_amdgcn_global_load_lds( \
        (const __attribute__((address_space(1))) void*)(gptr), \
        (__attribute__((address_space(3))) void*)(lptr), 16, 0, 0)

// MFMA lane layouts (gfx950, m89/m120-verified):
//   A[m=lane&15][k=quad*8+j], B[k=quad*8+j][n=lane&15], D[row=quad*4+reg][col=lane&15]

// ---------------------------------------------------------------------------
// W fp32 -> bf16 precvt. wb lives in d_out scratch (attn fully overwrites out
// afterwards; proj only reads wb). [mat][d][c] row-major.
__global__ __launch_bounds__(256) void wcvt_kernel(
    const float* __restrict__ wq, const float* __restrict__ wk,
    const float* __restrict__ wv, bf16_t* __restrict__ wb)
{
    const int mat = blockIdx.y;
    const float* __restrict__ W = (mat == 0) ? wq : (mat == 1 ? wk : wv);
    const int idx = (blockIdx.x * 256 + threadIdx.x) * 4;
    const float4 v = *(const float4*)&W[idx];
    bf16x4 pk;
    pk[0] = (bf16_t)v.x; pk[1] = (bf16_t)v.y;
    pk[2] = (bf16_t)v.z; pk[3] = (bf16_t)v.w;
    *(bf16x4*)&wb[(size_t)mat * 65536 + idx] = pk;
}

// ---------------------------------------------------------------------------
// Projection v3: out[n][d] = sum_c W[d][c]*X[b][c][n] + b[d]
// B-frags (W) straight from global bf16 (L2-resident, no Wl staging, no per-cs
// barriers). Xt slot-XOR swizzled (write conflicts 16->4-way, reads clean).
// OutL layout per mat: Q/K -> [64 n][264 d] (b128 conflict-free gather);
// V -> [256 d][72 n] (unchanged path).
__global__ __launch_bounds__(256, 3) void proj_kernel(
    const float* __restrict__ x, const float* __restrict__ motion,
    const bf16_t* __restrict__ wb,
    const float* __restrict__ bq, const float* __restrict__ bk,
    const float* __restrict__ bv,
    bf16_t* __restrict__ qg, bf16_t* __restrict__ kg, bf16_t* __restrict__ vg)
{
    const int mat = blockIdx.y;
    const int b   = blockIdx.x & 7;
    const int n0  = (blockIdx.x >> 3) * 64;
    const float* __restrict__ src  = (mat == 0) ? x : motion;
    const bf16_t* __restrict__ W   = wb + (size_t)mat * 65536;
    const float* __restrict__ bias = (mat == 0) ? bq : (mat == 1 ? bk : bv);

    __shared__ __align__(16) unsigned char smem[37888];
    bf16_t* Xt    = (bf16_t*)smem;          // [64][264], 16B-slot swizzled
    bf16_t* OutL  = (bf16_t*)smem;          // reused after GEMM (see layouts)
    float*  biasL = (float*)(smem + 36864); // [256]

    const int tid  = threadIdx.x;
    const int w    = tid >> 6;
    const int lane = tid & 63;
    const int l16  = lane & 15;
    const int quad = lane >> 4;

    biasL[tid] = bias[tid];

    // stage Xt[n][c] = src[b][c][n0+n]; phys col = ((c>>3)^((n>>2)&7))*8 + (c&7)
    for (int it = 0; it < 16; ++it) {
        const int c  = it * 16 + (tid >> 4);
        const int j4 = (tid & 15) * 4;
        const float4 v = *(const float4*)&src[((size_t)b * CH + c) * NTOK + n0 + j4];
        const int g  = tid & 7;                  // (n>>2)&7 for n = j4..j4+3
        const int pc = (((c >> 3) ^ g) << 3) + (c & 7);
        Xt[(j4 + 0) * 264 + pc] = (bf16_t)v.x;
        Xt[(j4 + 1) * 264 + pc] = (bf16_t)v.y;
        Xt[(j4 + 2) * 264 + pc] = (bf16_t)v.z;
        Xt[(j4 + 3) * 264 + pc] = (bf16_t)v.w;
    }
    __syncthreads();

    // A-frags: n = w*16+l16, de-swizzle with g = (n>>2)&7
    bf16x8 af[8];
    {
        const int g = (4 * w + (l16 >> 2)) & 7;
        const bf16_t* xr = Xt + (w * 16 + l16) * 264;
        #pragma unroll
        for (int cs = 0; cs < 8; ++cs)
            af[cs] = *(const bf16x8*)(xr + (((cs * 4 + quad) ^ g) << 3));
    }

    fx4 acc[16];
    #pragma unroll
    for (int i = 0; i < 16; ++i) acc[i] = (fx4){0.f, 0.f, 0.f, 0.f};

    // B-frags direct from global: W[d = dp*16+l16][cs*32 + quad*8 .. +8]
    #pragma unroll 1
    for (int dp = 0; dp < 16; ++dp) {
        const bf16_t* wr = W + ((size_t)(dp * 16 + l16)) * 256 + quad * 8;
        bf16x8 bfr[8];
        #pragma unroll
        for (int cs = 0; cs < 8; ++cs)
            bfr[cs] = *(const bf16x8*)(wr + cs * 32);
        #pragma unroll
        for (int cs = 0; cs < 8; ++cs)
            acc[dp] = __builtin_amdgcn_mfma_f32_16x16x32_bf16(af[cs], bfr[cs], acc[dp], 0, 0, 0);
    }

    __syncthreads();   // all waves done reading Xt (OutL aliases it)

    const float qs = (mat == 0) ? 0.0625f : 1.0f;   // softmax scale folded into Q

    if (mat < 2) {
        // OutL[n 64][264 d]: scalar writes ~4-way (cheap), b128 gather clean
        #pragma unroll
        for (int dp = 0; dp < 16; ++dp) {
            const int d = dp * 16 + l16;
            const float bb = biasL[d];
            #pragma unroll
            for (int r = 0; r < 4; ++r)
                OutL[(w * 16 + quad * 4 + r) * 264 + d] = (bf16_t)((acc[dp][r] + bb) * qs);
        }
        __syncthreads();
        bf16_t* __restrict__ G = (mat == 0) ? qg : kg;
        for (int it = 0; it < 8; ++it) {
            const int n  = it * 8 + (tid >> 5);
            const int d8 = (tid & 31) * 8;
            const bf16x8 vv = *(const bf16x8*)&OutL[n * 264 + d8];
            *(bf16x8*)&G[((size_t)b * NTOK + n0 + n) * CH + d8] = vv;
        }
    } else {
        // OutL[256 d][72 n]: b64 pk writes, b128 row reads (unchanged path)
        #pragma unroll
        for (int dp = 0; dp < 16; ++dp) {
            const int d = dp * 16 + l16;
            const float bb = biasL[d];
            bf16x4 pk;
            #pragma unroll
            for (int r = 0; r < 4; ++r)
                pk[r] = (bf16_t)(acc[dp][r] + bb);
            *(bf16x4*)&OutL[d * 72 + w * 16 + quad * 4] = pk;
        }
        __syncthreads();
        for (int it = 0; it < 8; ++it) {
            const int d  = it * 32 + (tid >> 3);
            const int n8 = (tid & 7) * 8;
            const bf16x8 vv = *(const bf16x8*)&OutL[d * 72 + n8];
            *(bf16x8*)&vg[((size_t)b * CH + d) * NTOK + n0 + n8] = vv;
        }
    }
}

// ---------------------------------------------------------------------------
// Attention v3: counted-vmcnt pipeline.
// Per tile t (p = t&1):
//   vmcnt(4) [drain K(t), V(t) keeps flying]; barrier1
//   QK(t) <- K ; exp ; packed P-write
//   vmcnt(0) lgkmcnt(0); barrier2
//   issue K(t+1)->K (single buf: QK(t) readers all behind barrier2),
//   issue V(t+1)->V[p^1] (double buf)
//   PV(t) <- V[p], P
// K flight = PV phase; V flight = PV + QK phases. No vmcnt(0)-drain of fresh
// stages at any barrier. Hazards: all K/V/P WAR-RAW pairs separated by b1/b2.
// Swizzles: K slot ^= (j&7); V slot ^= ((c>>1)&3)  (conflict-free per
// 8-lane cycle group, incl. row parity). P writes packed u32 (2-way = free).
// LDS: K@0 16K | V0@16K | V1@32K | P[64][40]@48K | lred@53K  -> 54784 B
__global__ __launch_bounds__(256, 2) void attn_kernel(
    const bf16_t* __restrict__ qg, const bf16_t* __restrict__ kg,
    const bf16_t* __restrict__ vg, float* __restrict__ out)
{
    const int b  = blockIdx.x & 7;     // batch -> XCD locality
    const int i0 = (blockIdx.x >> 3) * 64;

    __shared__ __align__(16) unsigned char smem[54784];
    bf16_t* const Kb   = (bf16_t*)smem;               // [32][256] swizzled
    bf16_t* const V0   = (bf16_t*)(smem + 16384);     // [256][32] swizzled
    bf16_t* const V1   = (bf16_t*)(smem + 32768);
    bf16_t* const P    = (bf16_t*)(smem + 49152);     // [64][40]
    float*  const lred = (float*)(smem + 54272);      // [2][64]

    const int tid  = threadIdx.x;
    const int w    = tid >> 6;
    const int lane = tid & 63;
    const int l16  = lane & 15;
    const int quad = lane >> 4;
    const int ih   = w & 1;      // QK i-half
    const int jh   = w >> 1;     // QK j-half
    const int ch   = w & 1;      // PV c-half
    const int is2  = w >> 1;     // PV i-half
    const int w4   = w * 4;

    // Q A-frags: rows i0 + ih*32 + isub*16 + l16
    bf16x8 qf[2][8];
    #pragma unroll
    for (int isub = 0; isub < 2; ++isub) {
        const bf16_t* qb = qg + ((size_t)b * NTOK + i0 + ih * 32 + isub * 16 + l16) * CH;
        #pragma unroll
        for (int cs = 0; cs < 8; ++cs)
            qf[isub][cs] = *(const bf16x8*)(qb + cs * 32 + quad * 8);
    }

    fx4 oacc[8][2];
    #pragma unroll
    for (int i = 0; i < 8; ++i) {
        oacc[i][0] = (fx4){0.f, 0.f, 0.f, 0.f};
        oacc[i][1] = (fx4){0.f, 0.f, 0.f, 0.f};
    }
    float rs0[4] = {0.f, 0.f, 0.f, 0.f};
    float rs1[4] = {0.f, 0.f, 0.f, 0.f};

    const int jrow = jh * 16 + l16;                      // K row (QK)
    const int sxk  = l16 & 7;                            // K read swizzle
    const int svo  = (quad ^ ((l16 >> 1) & 3)) * 8;      // V read swizzle (elems)
    const int vsl  = (lane & 3) ^ ((lane >> 3) & 3);     // V stage source slot

    auto stageK = [&](int t) {
        const int j0 = t * 32;
        #pragma unroll
        for (int it = 0; it < 4; ++it) {
            const int N   = w4 + it;
            const int kj  = 2 * N + (lane >> 5);
            const int ksl = (lane & 31) ^ (kj & 7);
            GLOAD_LDS16(kg + (((size_t)b * NTOK + j0 + kj) << 8) + ksl * 8, Kb + N * 512);
        }
    };
    auto stageV = [&](bf16_t* Vb, int t) {
        const int j0 = t * 32;
        #pragma unroll
        for (int it = 0; it < 4; ++it) {
            const int N  = w4 + it;
            const int vc = N * 16 + (lane >> 2);
            GLOAD_LDS16(vg + (((size_t)b * CH + vc) << 12) + j0 + vsl * 8, Vb + N * 512);
        }
    };

    // prologue: K(0) first (oldest 4 -> drained by vmcnt(4)), then V(0)
    stageK(0);
    stageV(V0, 0);

    auto tile = [&](bf16_t* const Vc, bf16_t* const Vn, const int t) {
        asm volatile("s_waitcnt vmcnt(4)" ::: "memory");   // K(t) done, V(t) flying
        __builtin_amdgcn_s_barrier();
        __builtin_amdgcn_sched_barrier(0);

        // QK: S[ih-half 32][jh-half 16]; K-frag feeds both i sub-strips
        fx4 s0 = (fx4){0.f, 0.f, 0.f, 0.f};
        fx4 s1 = (fx4){0.f, 0.f, 0.f, 0.f};
        {
            const bf16_t* krow = Kb + jrow * 256;
            __builtin_amdgcn_s_setprio(1);
            #pragma unroll
            for (int cs = 0; cs < 8; ++cs) {
                const bf16x8 kf = *(const bf16x8*)(krow + (((cs * 4 + quad) ^ sxk) * 8));
                s0 = __builtin_amdgcn_mfma_f32_16x16x32_bf16(qf[0][cs], kf, s0, 0, 0, 0);
                s1 = __builtin_amdgcn_mfma_f32_16x16x32_bf16(qf[1][cs], kf, s1, 0, 0, 0);
            }
            __builtin_amdgcn_s_setprio(0);
        }
        // exp + rowsums + packed P write (u32, lane pairs along j; 2-way = free)
        {
            bf16_t* prow = P + (ih * 32 + quad * 4) * 40 + jh * 16 + (l16 & ~1);
            #pragma unroll
            for (int r = 0; r < 4; ++r) {
                const float p0 = __expf(s0[r]);
                const float p1 = __expf(s1[r]);
                rs0[r] += p0;
                rs1[r] += p1;
                const float n0f = __shfl_xor(p0, 1);
                const float n1f = __shfl_xor(p1, 1);
                unsigned int pk0, pk1;
                asm("v_cvt_pk_bf16_f32 %0, %1, %2" : "=v"(pk0) : "v"(p0), "v"(n0f));
                asm("v_cvt_pk_bf16_f32 %0, %1, %2" : "=v"(pk1) : "v"(p1), "v"(n1f));
                if (!(l16 & 1)) {
                    *(unsigned int*)(prow + r * 40)       = pk0;  // row +r
                    *(unsigned int*)(prow + r * 40 + 640) = pk1;  // row +16+r
                }
            }
        }
        asm volatile("s_waitcnt vmcnt(0) lgkmcnt(0)" ::: "memory");  // V(t) + P done
        __builtin_amdgcn_s_barrier();
        __builtin_amdgcn_sched_barrier(0);

        // prefetch next tile in PV's shadow (K first: oldest for vmcnt(4))
        if (t + 1 < 128) {
            stageK(t + 1);
            stageV(Vn, t + 1);
        }

        // PV: O[c-half 128][i-half 32] += V * P^T; V-frag feeds 2 i-strips
        {
            const bf16x8 pf0 = *(const bf16x8*)(P + (is2 * 32 + l16) * 40 + quad * 8);
            const bf16x8 pf1 = *(const bf16x8*)(P + (is2 * 32 + 16 + l16) * 40 + quad * 8);
            const bf16_t* vbase = Vc + (ch * 128 + l16) * 32 + svo;
            __builtin_amdgcn_s_setprio(1);
            #pragma unroll
            for (int cp8 = 0; cp8 < 8; ++cp8) {
                const bf16x8 vf = *(const bf16x8*)(vbase + cp8 * 512);
                oacc[cp8][0] = __builtin_amdgcn_mfma_f32_16x16x32_bf16(vf, pf0, oacc[cp8][0], 0, 0, 0);
                oacc[cp8][1] = __builtin_amdgcn_mfma_f32_16x16x32_bf16(vf, pf1, oacc[cp8][1], 0, 0, 0);
            }
            __builtin_amdgcn_s_setprio(0);
        }
    };

    #pragma unroll 1
    for (int t = 0; t < 128; t += 2) {
        tile(V0, V1, t);
        tile(V1, V0, t + 1);
    }

    // rowsum: butterfly over 16 j-lanes, combine jh halves via LDS
    #pragma unroll
    for (int r = 0; r < 4; ++r) {
        float v0 = rs0[r], v1 = rs1[r];
        v0 += __shfl_xor(v0, 1); v0 += __shfl_xor(v0, 2);
        v0 += __shfl_xor(v0, 4); v0 += __shfl_xor(v0, 8);
        v1 += __shfl_xor(v1, 1); v1 += __shfl_xor(v1, 2);
        v1 += __shfl_xor(v1, 4); v1 += __shfl_xor(v1, 8);
        rs0[r] = v0; rs1[r] = v1;
    }
    __syncthreads();   // loop's raw barriers done; safe ordering for lred
    if (l16 == 0) {
        #pragma unroll
        for (int r = 0; r < 4; ++r) {
            lred[jh * 64 + ih * 32 + quad * 4 + r]      = rs0[r];
            lred[jh * 64 + ih * 32 + 16 + quad * 4 + r] = rs1[r];
        }
    }
    __syncthreads();

    const int   row0  = is2 * 32 + l16;
    const float linv0 = 1.0f / (lred[row0] + lred[64 + row0]);
    const float linv1 = 1.0f / (lred[row0 + 16] + lred[64 + row0 + 16]);

    // O store: c = (ch*8+cp8)*16 + quad*4 + r, i = i0 + is2*32 (+16) + l16
    const size_t obase = (size_t)b * CH * NTOK + i0 + is2 * 32 + l16;
    #pragma unroll
    for (int cp8 = 0; cp8 < 8; ++cp8) {
        const int c0 = (ch * 8 + cp8) * 16 + quad * 4;
        #pragma unroll
        for (int r = 0; r < 4; ++r) {
            out[obase + (size_t)(c0 + r) * NTOK]      = oacc[cp8][0][r] * linv0;
            out[obase + (size_t)(c0 + r) * NTOK + 16] = oacc[cp8][1][r] * linv1;
        }
    }
}

// ---------------------------------------------------------------------------
extern "C" void kernel_launch(void* const* d_in, const int* in_sizes, int n_in,
                              void* d_out, int out_size, void* d_ws, size_t ws_size,
                              hipStream_t stream) {
    const float* x  = (const float*)d_in[0];
    const float* mi = (const float*)d_in[1];
    const float* wq = (const float*)d_in[2];
    const float* bq = (const float*)d_in[3];
    const float* wk = (const float*)d_in[4];
    const float* bk = (const float*)d_in[5];
    const float* wv = (const float*)d_in[6];
    const float* bv = (const float*)d_in[7];

    bf16_t* qg = (bf16_t*)d_ws;
    bf16_t* kg = qg + (size_t)BATCH * NTOK * CH;
    bf16_t* vg = kg + (size_t)BATCH * NTOK * CH;
    bf16_t* wb = (bf16_t*)d_out;   // scratch: fully overwritten by attn later

    dim3 wgrid(64, 3);
    wcvt_kernel<<<wgrid, 256, 0, stream>>>(wq, wk, wv, wb);

    dim3 pgrid(BATCH * (NTOK / 64), 3);
    proj_kernel<<<pgrid, 256, 0, stream>>>(x, mi, wb, bq, bk, bv, qg, kg, vg);

    attn_kernel<<<BATCH * (NTOK / 64), 256, 0, stream>>>(qg, kg, vg, (float*)d_out);
}

// Round 4
// 378.425 us; speedup vs baseline: 1.1465x; 1.1465x over previous
//
#include <hip/hip_runtime.h>
#include <hip/hip_bf16.h>

#define BATCH 8
#define CH    256
#define NTOK  4096

typedef __bf16 bf16_t;
typedef __bf16 bf16x8 __attribute__((ext_vector_type(8)));
typedef __bf16 bf16x4 __attribute__((ext_vector_type(4)));
typedef float  fx4    __attribute__((ext_vector_type(4)));

// async global->LDS, 16B per lane, dest = wave-uniform base + lane*16
#define GLOAD_LDS16(gptr, lptr) \
    __builtin_amdgcn_global_load_lds( \
        (const __attribute__((address_space(1))) void*)(gptr), \
        (__attribute__((address_space(3))) void*)(lptr), 16, 0, 0)

// MFMA lane layouts (gfx950, m89/m120-verified):
//   A[m=lane&15][k=quad*8+j], B[k=quad*8+j][n=lane&15], D[row=quad*4+reg][col=lane&15]

// ---------------------------------------------------------------------------
// W fp32 -> bf16 precvt into d_out scratch (attn overwrites out afterwards).
__global__ __launch_bounds__(256) void wcvt_kernel(
    const float* __restrict__ wq, const float* __restrict__ wk,
    const float* __restrict__ wv, bf16_t* __restrict__ wb)
{
    const int mat = blockIdx.y;
    const float* __restrict__ W = (mat == 0) ? wq : (mat == 1 ? wk : wv);
    const int idx = (blockIdx.x * 256 + threadIdx.x) * 4;
    const float4 v = *(const float4*)&W[idx];
    bf16x4 pk;
    pk[0] = (bf16_t)v.x; pk[1] = (bf16_t)v.y;
    pk[2] = (bf16_t)v.z; pk[3] = (bf16_t)v.w;
    *(bf16x4*)&wb[(size_t)mat * 65536 + idx] = pk;
}

// ---------------------------------------------------------------------------
// Projection v4: one block per (b, n-tile 64) computes Q, K, V (motion staged
// once). A-frags (x, motion) live in registers; W B-frags direct from L2
// (bf16, 384 KB total resident). dp-loop FULLY unrolled (static acc — rule
// #20: unroll-1 + acc[dp] was R2's scratch-spill regression).
// LDS: Xt[64][264] swz @0 | Mt[64][264] swz @33792 | biasL[3][256] @67584.
// OutL aliases: Q/K -> [64][264] @0 ; V -> [256][72] @0 (Mt dead by then).
__global__ __launch_bounds__(256, 2) void proj_kernel(
    const float* __restrict__ x, const float* __restrict__ motion,
    const bf16_t* __restrict__ wb,
    const float* __restrict__ bq, const float* __restrict__ bk,
    const float* __restrict__ bv,
    bf16_t* __restrict__ qg, bf16_t* __restrict__ kg, bf16_t* __restrict__ vg)
{
    const int b  = blockIdx.x & 7;
    const int n0 = (blockIdx.x >> 3) * 64;

    __shared__ __align__(16) unsigned char smem[70656];
    bf16_t* Xt    = (bf16_t*)smem;              // [64][264] 16B-slot swizzled
    bf16_t* Mt    = (bf16_t*)(smem + 33792);    // [64][264] 16B-slot swizzled
    float*  biasL = (float*)(smem + 67584);     // [3][256]
    bf16_t* OutQK = (bf16_t*)smem;              // [64][264] alias
    bf16_t* OutV  = (bf16_t*)smem;              // [256][72] alias

    const int tid  = threadIdx.x;
    const int w    = tid >> 6;
    const int lane = tid & 63;
    const int l16  = lane & 15;
    const int quad = lane >> 4;

    biasL[tid]       = bq[tid];
    biasL[tid + 256] = bk[tid];
    biasL[tid + 512] = bv[tid];

    // stage Xt/Mt: dst[n][c], phys col chunk = (c>>3) ^ ((n>>2)&7)
    #pragma unroll
    for (int s = 0; s < 2; ++s) {
        const float* __restrict__ src = s ? motion : x;
        bf16_t* dst = s ? Mt : Xt;
        for (int it = 0; it < 16; ++it) {
            const int c  = it * 16 + (tid >> 4);
            const int j4 = (tid & 15) * 4;
            const float4 v = *(const float4*)&src[((size_t)b * CH + c) * NTOK + n0 + j4];
            const int g  = tid & 7;                  // (n>>2)&7 for n = j4..j4+3
            const int pc = (((c >> 3) ^ g) << 3) + (c & 7);
            dst[(j4 + 0) * 264 + pc] = (bf16_t)v.x;
            dst[(j4 + 1) * 264 + pc] = (bf16_t)v.y;
            dst[(j4 + 2) * 264 + pc] = (bf16_t)v.z;
            dst[(j4 + 3) * 264 + pc] = (bf16_t)v.w;
        }
    }
    __syncthreads();

    // A-frags into regs: n = w*16 + l16, de-swizzle with g = (n>>2)&7
    bf16x8 ax[8], am[8];
    {
        const int g = (4 * w + (l16 >> 2)) & 7;
        const bf16_t* xr = Xt + (w * 16 + l16) * 264;
        const bf16_t* mr = Mt + (w * 16 + l16) * 264;
        #pragma unroll
        for (int cs = 0; cs < 8; ++cs) {
            const int off = ((cs * 4 + quad) ^ g) << 3;
            ax[cs] = *(const bf16x8*)(xr + off);
            am[cs] = *(const bf16x8*)(mr + off);
        }
    }
    __syncthreads();   // all frag reads done; OutL regions may be overwritten

    fx4 acc[16];

    auto gemm = [&](const bf16x8* af, const bf16_t* __restrict__ Wm) {
        #pragma unroll
        for (int i = 0; i < 16; ++i) acc[i] = (fx4){0.f, 0.f, 0.f, 0.f};
        #pragma unroll
        for (int dp = 0; dp < 16; ++dp) {   // FULL unroll: acc/bfr all static
            const bf16_t* wr = Wm + ((size_t)(dp * 16 + l16) << 8) + quad * 8;
            bf16x8 bfr[8];
            #pragma unroll
            for (int cs = 0; cs < 8; ++cs)
                bfr[cs] = *(const bf16x8*)(wr + cs * 32);
            #pragma unroll
            for (int cs = 0; cs < 8; ++cs)
                acc[dp] = __builtin_amdgcn_mfma_f32_16x16x32_bf16(af[cs], bfr[cs], acc[dp], 0, 0, 0);
        }
    };

    // ---- Q ----
    gemm(ax, wb);
    #pragma unroll
    for (int dp = 0; dp < 16; ++dp) {
        const int d = dp * 16 + l16;
        const float bb = biasL[d];
        #pragma unroll
        for (int r = 0; r < 4; ++r)
            OutQK[(w * 16 + quad * 4 + r) * 264 + d] = (bf16_t)((acc[dp][r] + bb) * 0.0625f);
    }
    __syncthreads();
    #pragma unroll
    for (int it = 0; it < 8; ++it) {
        const int n  = it * 8 + (tid >> 5);
        const int d8 = (tid & 31) * 8;
        const bf16x8 vv = *(const bf16x8*)&OutQK[n * 264 + d8];
        *(bf16x8*)&qg[((size_t)b * NTOK + n0 + n) * CH + d8] = vv;
    }

    // ---- K ---- (gemm has no LDS deps; overlaps the Q gather above)
    gemm(am, wb + 65536);
    __syncthreads();   // Q-gather reads retired before K OutQK writes
    #pragma unroll
    for (int dp = 0; dp < 16; ++dp) {
        const int d = dp * 16 + l16;
        const float bb = biasL[256 + d];
        #pragma unroll
        for (int r = 0; r < 4; ++r)
            OutQK[(w * 16 + quad * 4 + r) * 264 + d] = (bf16_t)(acc[dp][r] + bb);
    }
    __syncthreads();
    #pragma unroll
    for (int it = 0; it < 8; ++it) {
        const int n  = it * 8 + (tid >> 5);
        const int d8 = (tid & 31) * 8;
        const bf16x8 vv = *(const bf16x8*)&OutQK[n * 264 + d8];
        *(bf16x8*)&kg[((size_t)b * NTOK + n0 + n) * CH + d8] = vv;
    }

    // ---- V ---- (gemm overlaps the K gather)
    gemm(am, wb + 131072);
    __syncthreads();   // K-gather reads retired before OutV writes
    #pragma unroll
    for (int dp = 0; dp < 16; ++dp) {
        const int d = dp * 16 + l16;
        const float bb = biasL[512 + d];
        bf16x4 pk;
        #pragma unroll
        for (int r = 0; r < 4; ++r)
            pk[r] = (bf16_t)(acc[dp][r] + bb);
        *(bf16x4*)&OutV[d * 72 + w * 16 + quad * 4] = pk;
    }
    __syncthreads();
    #pragma unroll
    for (int it = 0; it < 8; ++it) {
        const int d  = it * 32 + (tid >> 3);
        const int n8 = (tid & 7) * 8;
        const bf16x8 vv = *(const bf16x8*)&OutV[d * 72 + n8];
        *(bf16x8*)&vg[((size_t)b * CH + d) * NTOK + n0 + n8] = vv;
    }
}

// ---------------------------------------------------------------------------
// Attention v4: counted-vmcnt pipeline with FULL-TILE flight windows.
// K and V both double-buffered. Per tile t:
//   issue K(t+1)->Kn ; vmcnt(8) [drain K(t) only] ; barrier A
//   issue V(t+1)->Vn ; QK(t) ; exp ; packed P write
//   vmcnt(8) lgkmcnt(0) [drain V(t) only] ; barrier B ; PV(t)
// Flights: K(t+1) = A..top(t+1) (~full tile); V(t+1) = QK(t)..mid(t+1).
// Last tile peeled with vmcnt(4)/vmcnt(0). Hazards: every WAR/RAW pair on
// K/V/P is separated by barrier A or B (re-derived; see comments inline).
// LDS: K0@0 K1@16K | V0@32K V1@48K | P[64][40]@64K | lred@69.5K = 71168 B
__global__ __launch_bounds__(256, 2) void attn_kernel(
    const bf16_t* __restrict__ qg, const bf16_t* __restrict__ kg,
    const bf16_t* __restrict__ vg, float* __restrict__ out)
{
    const int b  = blockIdx.x & 7;     // batch -> XCD locality
    const int i0 = (blockIdx.x >> 3) * 64;

    __shared__ __align__(16) unsigned char smem[71168];
    bf16_t* const K0   = (bf16_t*)smem;               // [32][256] swizzled
    bf16_t* const K1   = (bf16_t*)(smem + 16384);
    bf16_t* const V0   = (bf16_t*)(smem + 32768);     // [256][32] swizzled
    bf16_t* const V1   = (bf16_t*)(smem + 49152);
    bf16_t* const P    = (bf16_t*)(smem + 65536);     // [64][40]
    float*  const lred = (float*)(smem + 70656);      // [2][64]

    const int tid  = threadIdx.x;
    const int w    = tid >> 6;
    const int lane = tid & 63;
    const int l16  = lane & 15;
    const int quad = lane >> 4;
    const int ih   = w & 1;      // QK i-half
    const int jh   = w >> 1;     // QK j-half
    const int ch   = w & 1;      // PV c-half
    const int is2  = w >> 1;     // PV i-half
    const int w4   = w * 4;

    // Q A-frags: rows i0 + ih*32 + isub*16 + l16 (scale folded into Q)
    bf16x8 qf[2][8];
    #pragma unroll
    for (int isub = 0; isub < 2; ++isub) {
        const bf16_t* qb = qg + ((size_t)b * NTOK + i0 + ih * 32 + isub * 16 + l16) * CH;
        #pragma unroll
        for (int cs = 0; cs < 8; ++cs)
            qf[isub][cs] = *(const bf16x8*)(qb + cs * 32 + quad * 8);
    }

    fx4 oacc[8][2];
    #pragma unroll
    for (int i = 0; i < 8; ++i) {
        oacc[i][0] = (fx4){0.f, 0.f, 0.f, 0.f};
        oacc[i][1] = (fx4){0.f, 0.f, 0.f, 0.f};
    }
    float rs0[4] = {0.f, 0.f, 0.f, 0.f};
    float rs1[4] = {0.f, 0.f, 0.f, 0.f};

    const int jrow = jh * 16 + l16;                      // K row (QK)
    const int sxk  = l16 & 7;                            // K read swizzle
    const int svo  = (quad ^ ((l16 >> 1) & 3)) * 8;      // V read swizzle (elems)
    const int vsl  = (lane & 3) ^ ((lane >> 3) & 3);     // V stage source slot

    auto stageK = [&](bf16_t* Kb, int t) {
        const int j0 = t * 32;
        #pragma unroll
        for (int it = 0; it < 4; ++it) {
            const int N   = w4 + it;
            const int kj  = 2 * N + (lane >> 5);
            const int ksl = (lane & 31) ^ (kj & 7);
            GLOAD_LDS16(kg + (((size_t)b * NTOK + j0 + kj) << 8) + ksl * 8, Kb + N * 512);
        }
    };
    auto stageV = [&](bf16_t* Vb, int t) {
        const int j0 = t * 32;
        #pragma unroll
        for (int it = 0; it < 4; ++it) {
            const int N  = w4 + it;
            const int vc = N * 16 + (lane >> 2);
            GLOAD_LDS16(vg + (((size_t)b * CH + vc) << 12) + j0 + vsl * 8, Vb + N * 512);
        }
    };

    // prologue: K(0) then V(0)  [K oldest in vmcnt queue]
    stageK(K0, 0);
    stageV(V0, 0);

    auto tile = [&](bf16_t* const Kc, bf16_t* const Kn,
                    bf16_t* const Vc, bf16_t* const Vn,
                    const int t, const bool last) {
        // K[Kn] last read by QK(t-1), drained by mid-tile lgkmcnt(0) before
        // barrier B(t-1) -> safe to overwrite now
        if (!last) stageK(Kn, t + 1);
        if (!last) { asm volatile("s_waitcnt vmcnt(8)" ::: "memory"); }  // K(t) done
        else       { asm volatile("s_waitcnt vmcnt(4)" ::: "memory"); }
        __builtin_amdgcn_s_barrier();          // A: PV(t-1) P/V reads done
        __builtin_amdgcn_sched_barrier(0);
        // V[Vn] last read by PV(t-1), retired (MFMA-consumed) before barrier A
        if (!last) stageV(Vn, t + 1);

        // QK: S[ih-half 32][jh-half 16]; K-frag feeds both i sub-strips
        fx4 s0 = (fx4){0.f, 0.f, 0.f, 0.f};
        fx4 s1 = (fx4){0.f, 0.f, 0.f, 0.f};
        {
            const bf16_t* krow = Kc + jrow * 256;
            __builtin_amdgcn_s_setprio(1);
            #pragma unroll
            for (int cs = 0; cs < 8; ++cs) {
                const bf16x8 kf = *(const bf16x8*)(krow + (((cs * 4 + quad) ^ sxk) * 8));
                s0 = __builtin_amdgcn_mfma_f32_16x16x32_bf16(qf[0][cs], kf, s0, 0, 0, 0);
                s1 = __builtin_amdgcn_mfma_f32_16x16x32_bf16(qf[1][cs], kf, s1, 0, 0, 0);
            }
            __builtin_amdgcn_s_setprio(0);
        }
        // exp + rowsums + packed P write (u32 pairs along j; conflict-free)
        {
            bf16_t* prow = P + (ih * 32 + quad * 4) * 40 + jh * 16 + (l16 & ~1);
            #pragma unroll
            for (int r = 0; r < 4; ++r) {
                const float p0 = __expf(s0[r]);
                const float p1 = __expf(s1[r]);
                rs0[r] += p0;
                rs1[r] += p1;
                const float n0f = __shfl_xor(p0, 1);
                const float n1f = __shfl_xor(p1, 1);
                unsigned int pk0, pk1;
                asm("v_cvt_pk_bf16_f32 %0, %1, %2" : "=v"(pk0) : "v"(p0), "v"(n0f));
                asm("v_cvt_pk_bf16_f32 %0, %1, %2" : "=v"(pk1) : "v"(p1), "v"(n1f));
                if (!(l16 & 1)) {
                    *(unsigned int*)(prow + r * 40)       = pk0;  // row ih*32+quad*4+r
                    *(unsigned int*)(prow + r * 40 + 640) = pk1;  // row +16
                }
            }
        }
        if (!last) { asm volatile("s_waitcnt vmcnt(8) lgkmcnt(0)" ::: "memory"); }  // V(t)+P done
        else       { asm volatile("s_waitcnt vmcnt(0) lgkmcnt(0)" ::: "memory"); }
        __builtin_amdgcn_s_barrier();          // B: P visible, V(t) landed
        __builtin_amdgcn_sched_barrier(0);

        // PV: O[c-half 128][i-half 32] += V * P^T; V-frag feeds 2 i-strips
        {
            const bf16x8 pf0 = *(const bf16x8*)(P + (is2 * 32 + l16) * 40 + quad * 8);
            const bf16x8 pf1 = *(const bf16x8*)(P + (is2 * 32 + 16 + l16) * 40 + quad * 8);
            const bf16_t* vbase = Vc + (ch * 128 + l16) * 32 + svo;
            __builtin_amdgcn_s_setprio(1);
            #pragma unroll
            for (int cp8 = 0; cp8 < 8; ++cp8) {
                const bf16x8 vf = *(const bf16x8*)(vbase + cp8 * 512);
                oacc[cp8][0] = __builtin_amdgcn_mfma_f32_16x16x32_bf16(vf, pf0, oacc[cp8][0], 0, 0, 0);
                oacc[cp8][1] = __builtin_amdgcn_mfma_f32_16x16x32_bf16(vf, pf1, oacc[cp8][1], 0, 0, 0);
            }
            __builtin_amdgcn_s_setprio(0);
        }
    };

    #pragma unroll 1
    for (int t = 0; t < 126; t += 2) {
        tile(K0, K1, V0, V1, t,     false);
        tile(K1, K0, V1, V0, t + 1, false);
    }
    tile(K0, K1, V0, V1, 126, false);
    tile(K1, K0, V1, V0, 127, true);

    // rowsum: butterfly over 16 j-lanes, combine jh halves via LDS
    #pragma unroll
    for (int r = 0; r < 4; ++r) {
        float v0 = rs0[r], v1 = rs1[r];
        v0 += __shfl_xor(v0, 1); v0 += __shfl_xor(v0, 2);
        v0 += __shfl_xor(v0, 4); v0 += __shfl_xor(v0, 8);
        v1 += __shfl_xor(v1, 1); v1 += __shfl_xor(v1, 2);
        v1 += __shfl_xor(v1, 4); v1 += __shfl_xor(v1, 8);
        rs0[r] = v0; rs1[r] = v1;
    }
    __syncthreads();
    if (l16 == 0) {
        #pragma unroll
        for (int r = 0; r < 4; ++r) {
            lred[jh * 64 + ih * 32 + quad * 4 + r]      = rs0[r];
            lred[jh * 64 + ih * 32 + 16 + quad * 4 + r] = rs1[r];
        }
    }
    __syncthreads();

    const int   row0  = is2 * 32 + l16;
    const float linv0 = 1.0f / (lred[row0] + lred[64 + row0]);
    const float linv1 = 1.0f / (lred[row0 + 16] + lred[64 + row0 + 16]);

    // O store: c = (ch*8+cp8)*16 + quad*4 + r, i = i0 + is2*32 (+16) + l16
    const size_t obase = (size_t)b * CH * NTOK + i0 + is2 * 32 + l16;
    #pragma unroll
    for (int cp8 = 0; cp8 < 8; ++cp8) {
        const int c0 = (ch * 8 + cp8) * 16 + quad * 4;
        #pragma unroll
        for (int r = 0; r < 4; ++r) {
            out[obase + (size_t)(c0 + r) * NTOK]      = oacc[cp8][0][r] * linv0;
            out[obase + (size_t)(c0 + r) * NTOK + 16] = oacc[cp8][1][r] * linv1;
        }
    }
}

// ---------------------------------------------------------------------------
extern "C" void kernel_launch(void* const* d_in, const int* in_sizes, int n_in,
                              void* d_out, int out_size, void* d_ws, size_t ws_size,
                              hipStream_t stream) {
    const float* x  = (const float*)d_in[0];
    const float* mi = (const float*)d_in[1];
    const float* wq = (const float*)d_in[2];
    const float* bq = (const float*)d_in[3];
    const float* wk = (const float*)d_in[4];
    const float* bk = (const float*)d_in[5];
    const float* wv = (const float*)d_in[6];
    const float* bv = (const float*)d_in[7];

    bf16_t* qg = (bf16_t*)d_ws;
    bf16_t* kg = qg + (size_t)BATCH * NTOK * CH;
    bf16_t* vg = kg + (size_t)BATCH * NTOK * CH;
    bf16_t* wb = (bf16_t*)d_out;   // scratch: fully overwritten by attn later

    dim3 wgrid(64, 3);
    wcvt_kernel<<<wgrid, 256, 0, stream>>>(wq, wk, wv, wb);

    proj_kernel<<<BATCH * (NTOK / 64), 256, 0, stream>>>(x, mi, wb, bq, bk, bv, qg, kg, vg);

    attn_kernel<<<BATCH * (NTOK / 64), 256, 0, stream>>>(qg, kg, vg, (float*)d_out);
}